// Round 5
// baseline (637.757 us; speedup 1.0000x reference)
//
#include <hip/hip_runtime.h>
#include <stdint.h>

#define LDIM 512
#define LLTOT 262144            // 512*512
#define EPSV 1e-5f

typedef short bf16x8 __attribute__((ext_vector_type(8)));
typedef float f32x4 __attribute__((ext_vector_type(4)));

__device__ __forceinline__ unsigned short f2bf(float f) {
  union { float f; unsigned u; } v; v.f = f;
  unsigned r = v.u + 0x7FFFu + ((v.u >> 16) & 1u);   // RNE
  return (unsigned short)(r >> 16);
}
__device__ __forceinline__ float bf2f(unsigned short h) {
  union { unsigned u; float f; } v; v.u = ((unsigned)h) << 16;
  return v.f;
}
__device__ __forceinline__ float sigm(float x) { return 1.0f / (1.0f + __expf(-x)); }

// Fragment-major layout for a/b intermediates (the einsum's operands):
//   element (ch, i, k) lives at
//   ch*524288 + (k>>5)*32768 + (i>>4)*1024 + ((i&15)*4 + ((k>>3)&3))*16 + (k&7)*2
// One (ch, k32, i16) chunk = 1 KB = exactly one wave's MFMA fragment load.

// ---------------------------------------------------------------------------
// K0: weights fp32 [c][o] -> bf16 transposed [o][c].  Order: ga,pa,gb,pb,go,po
// ---------------------------------------------------------------------------
__global__ void k_prep(const float* __restrict__ Wpa, const float* __restrict__ Wga,
                       const float* __restrict__ Wpb, const float* __restrict__ Wgb,
                       const float* __restrict__ Wgo, const float* __restrict__ Wpo,
                       unsigned short* __restrict__ Wt) {
  int t = blockIdx.x * blockDim.x + threadIdx.x;     // 0..98303
  int mat = t >> 14;
  int rem = t & 16383;
  int o = rem >> 7;
  int c = rem & 127;
  const float* src;
  switch (mat) {
    case 0: src = Wga; break;
    case 1: src = Wpa; break;
    case 2: src = Wgb; break;
    case 3: src = Wpb; break;
    case 4: src = Wgo; break;
    default: src = Wpo; break;
  }
  Wt[mat * 16384 + o * 128 + c] = f2bf(src[c * 128 + o]);
}

// ---------------------------------------------------------------------------
// K1 (fused LN + projections), weights-resident.  Per block: 64 flat positions
// (LDS 17.4 KB -> 8 blocks/CU for latency hiding).  a/b in FRAGMENT-MAJOR.
// ---------------------------------------------------------------------------
__global__ __launch_bounds__(256) void k_proj(const float* __restrict__ z,
                                              const float* __restrict__ lnw,
                                              const float* __restrict__ lnb,
                                              const unsigned short* __restrict__ Wt,
                                              const int* __restrict__ maskp,
                                              unsigned short* __restrict__ a_f,
                                              unsigned short* __restrict__ b_f,
                                              unsigned short* __restrict__ gout) {
  __shared__ unsigned char zbuf[64 * 272];    // rows padded 256->272B
  __shared__ float maskf[64];
  const int t = threadIdx.x;
  const int bid = blockIdx.x;
  const long r0 = (long)bid * 64;
  const int w = t >> 6, lane = t & 63;
  const int mn = lane & 15, q4 = lane >> 4;
  // fragment-layout constants for this block (i fixed, k0 = start col)
  const int k0 = (bid & 7) * 64;
  const int i16 = bid >> 7;            // (i>>4), i = bid>>3
  const int irem = (bid >> 3) & 15;    // i & 15

  if (t < 64) maskf[t] = (float)maskp[r0 + t];

  // fused input LayerNorm: each wave handles 16 rows; lane holds 2 channels
  const float lw0 = lnw[2 * lane], lw1 = lnw[2 * lane + 1];
  const float lb0 = lnb[2 * lane], lb1 = lnb[2 * lane + 1];
#pragma unroll
  for (int rr = 0; rr < 16; rr += 4) {
    float2 v[4];
#pragma unroll
    for (int i = 0; i < 4; ++i)
      v[i] = ((const float2*)(z + (r0 + w * 16 + rr + i) * 128))[lane];
#pragma unroll
    for (int i = 0; i < 4; ++i) {
      float s = v[i].x + v[i].y, q = v[i].x * v[i].x + v[i].y * v[i].y;
#pragma unroll
      for (int off = 32; off; off >>= 1) { s += __shfl_xor(s, off); q += __shfl_xor(q, off); }
      float mu = s * (1.0f / 128.0f);
      float rs = rsqrtf(q * (1.0f / 128.0f) - mu * mu + EPSV);
      ushort2 o;
      o.x = f2bf((v[i].x - mu) * rs * lw0 + lb0);
      o.y = f2bf((v[i].y - mu) * rs * lw1 + lb1);
      ((ushort2*)&zbuf[(w * 16 + rr + i) * 272])[lane] = o;
    }
  }
  __syncthreads();

  // phases p=0 (a), p=1 (b): gate+proj weights resident in VGPRs
#pragma unroll 1
  for (int p = 0; p < 2; ++p) {
    const unsigned short* Wg = Wt + (p * 2) * 16384;
    const unsigned short* Wp = Wt + (p * 2 + 1) * 16384;
    unsigned short* dst = p ? b_f : a_f;
    bf16x8 wg[2][4], wp[2][4];
#pragma unroll
    for (int ntl = 0; ntl < 2; ++ntl)
#pragma unroll
      for (int kk = 0; kk < 4; ++kk) {
        const int o = (w * 2 + ntl) * 16 + mn;
        wg[ntl][kk] = *(const bf16x8*)(Wg + o * 128 + kk * 32 + q4 * 8);
        wp[ntl][kk] = *(const bf16x8*)(Wp + o * 128 + kk * 32 + q4 * 8);
      }
#pragma unroll 1
    for (int rg = 0; rg < 4; ++rg) {
      bf16x8 afr[4];
#pragma unroll
      for (int kk = 0; kk < 4; ++kk)
        afr[kk] = *(const bf16x8*)(&zbuf[(rg * 16 + mn) * 272 + kk * 64 + q4 * 16]);
      f32x4 aG[2] = {{0.f,0.f,0.f,0.f},{0.f,0.f,0.f,0.f}};
      f32x4 aP[2] = {{0.f,0.f,0.f,0.f},{0.f,0.f,0.f,0.f}};
#pragma unroll
      for (int kk = 0; kk < 4; ++kk)
#pragma unroll
        for (int ntl = 0; ntl < 2; ++ntl) {
          aG[ntl] = __builtin_amdgcn_mfma_f32_16x16x32_bf16(afr[kk], wg[ntl][kk], aG[ntl], 0, 0, 0);
          aP[ntl] = __builtin_amdgcn_mfma_f32_16x16x32_bf16(afr[kk], wp[ntl][kk], aP[ntl], 0, 0, 0);
        }
      const int rowb = rg * 16 + q4 * 4;        // k-offset within block (4 consec)
      const int kpos = k0 + rowb;               // global k of first element
      const int kc = kpos >> 5;
      const int cell = (irem * 4 + ((kpos >> 3) & 3)) * 16 + (kpos & 7) * 2;
#pragma unroll
      for (int ntl = 0; ntl < 2; ++ntl) {
        const int c = (w * 2 + ntl) * 16 + mn;
        unsigned short hv[4];
#pragma unroll
        for (int r = 0; r < 4; ++r)
          hv[r] = f2bf(sigm(aG[ntl][r]) * aP[ntl][r] * maskf[rowb + r]);
        uint2 pk;
        pk.x = (unsigned)hv[0] | ((unsigned)hv[1] << 16);
        pk.y = (unsigned)hv[2] | ((unsigned)hv[3] << 16);
        *(uint2*)((char*)dst + (long)c * 524288 + kc * 32768 + i16 * 1024 + cell) = pk;
      }
    }
  }

  {  // g phase: g = sigmoid(zln @ Wgo) -> gout[row][c] (direct 2B stores, L2 merges)
    const unsigned short* Wgp = Wt + 4 * 16384;
    bf16x8 wg[2][4];
#pragma unroll
    for (int ntl = 0; ntl < 2; ++ntl)
#pragma unroll
      for (int kk = 0; kk < 4; ++kk)
        wg[ntl][kk] = *(const bf16x8*)(Wgp + ((w * 2 + ntl) * 16 + mn) * 128 + kk * 32 + q4 * 8);
#pragma unroll 1
    for (int rg = 0; rg < 4; ++rg) {
      bf16x8 afr[4];
#pragma unroll
      for (int kk = 0; kk < 4; ++kk)
        afr[kk] = *(const bf16x8*)(&zbuf[(rg * 16 + mn) * 272 + kk * 64 + q4 * 16]);
      f32x4 aG[2] = {{0.f,0.f,0.f,0.f},{0.f,0.f,0.f,0.f}};
#pragma unroll
      for (int kk = 0; kk < 4; ++kk)
#pragma unroll
        for (int ntl = 0; ntl < 2; ++ntl)
          aG[ntl] = __builtin_amdgcn_mfma_f32_16x16x32_bf16(afr[kk], wg[ntl][kk], aG[ntl], 0, 0, 0);
      const int rowb = rg * 16 + q4 * 4;
#pragma unroll
      for (int ntl = 0; ntl < 2; ++ntl) {
        const int c = (w * 2 + ntl) * 16 + mn;
#pragma unroll
        for (int r = 0; r < 4; ++r)
          gout[(r0 + rowb + r) * 128 + c] = f2bf(sigm(aG[ntl][r]));
      }
    }
  }
}

// ---------------------------------------------------------------------------
// K3: per-channel GEMM  m_c = a_c @ b_c^T from FRAGMENT-MAJOR operands.
// No LDS staging, no barriers; double-buffered direct fragment loads.
// Epilogue bounce shrunk to 4.5 KB/wave (two half-tile passes) -> 18.4 KB LDS.
// ---------------------------------------------------------------------------
__global__ __launch_bounds__(256) void k_einsum(const unsigned short* __restrict__ af_g,
                                                const unsigned short* __restrict__ bf_g,
                                                unsigned short* __restrict__ m_t) {
  __shared__ unsigned char shm[18432];   // 4 waves x 4608B epilogue bounce
  const int t = threadIdx.x;
  const int w = t >> 6, lane = t & 63;
  const int bid = blockIdx.x;
  const int xcd = bid & 7;               // round-robin bid%8 -> XCD
  const int j = bid >> 3;
  const int ch = xcd * 16 + (j >> 4);    // 16 channels per XCD
  const int tile = j & 15;
  const int ti = tile >> 2, tj = tile & 3;
  const int wr = w >> 1, wc = w & 1;
  const int mn = lane & 15, q4 = lane >> 4;
  const int loff = (mn * 4 + q4) * 16;   // cell order: (i&15)*4 + k-subchunk
  const char* Af = (const char*)af_g + (long)ch * 524288 + (ti * 8 + wr * 4) * 1024 + loff;
  const char* Bf = (const char*)bf_g + (long)ch * 524288 + (tj * 8 + wc * 4) * 1024 + loff;

  f32x4 acc[4][4];
#pragma unroll
  for (int i = 0; i < 4; ++i)
#pragma unroll
    for (int jj = 0; jj < 4; ++jj) acc[i][jj] = (f32x4){0.f, 0.f, 0.f, 0.f};

  bf16x8 afr[2][4], bfr[2][4];
#define LOADFRAG(buf, k32)                                                    \
  {                                                                           \
    _Pragma("unroll")                                                         \
    for (int mt = 0; mt < 4; ++mt)                                            \
      afr[buf][mt] = *(const bf16x8*)(Af + (k32) * 32768 + mt * 1024);        \
    _Pragma("unroll")                                                         \
    for (int nt = 0; nt < 4; ++nt)                                            \
      bfr[buf][nt] = *(const bf16x8*)(Bf + (k32) * 32768 + nt * 1024);        \
  }
#define MFMABLK(buf)                                                          \
  {                                                                           \
    _Pragma("unroll")                                                         \
    for (int mt = 0; mt < 4; ++mt)                                            \
      _Pragma("unroll")                                                       \
      for (int nt = 0; nt < 4; ++nt)                                          \
        acc[mt][nt] = __builtin_amdgcn_mfma_f32_16x16x32_bf16(                \
            afr[buf][mt], bfr[buf][nt], acc[mt][nt], 0, 0, 0);                \
  }

  LOADFRAG(0, 0)
#pragma unroll 1
  for (int k32 = 0; k32 < 14; k32 += 2) {
    LOADFRAG(1, k32 + 1)
    MFMABLK(0)
    LOADFRAG(0, k32 + 2)
    MFMABLK(1)
  }
  LOADFRAG(1, 15)
  MFMABLK(0)
  MFMABLK(1)
#undef LOADFRAG
#undef MFMABLK

  // epilogue: wave-private LDS bounce, two 32-row passes (no syncs needed)
  unsigned char* eb = shm + w * 4608;    // 32 rows x 144B
  char* Mg = (char*)m_t + (long)ch * 524288 +
             (long)(ti * 128 + wr * 64) * 1024 + (tj * 128 + wc * 64) * 2;
#pragma unroll 1
  for (int half = 0; half < 2; ++half) {
#pragma unroll
    for (int mh = 0; mh < 2; ++mh) {
      const int mt = half * 2 + mh;
#pragma unroll
      for (int nt = 0; nt < 4; ++nt)
#pragma unroll
        for (int r = 0; r < 4; ++r) {
          int rl = mh * 16 + q4 * 4 + r;
          int cl = nt * 16 + mn;
          *(unsigned short*)(&eb[rl * 144 + cl * 2]) = f2bf(acc[mt][nt][r]);
        }
    }
#pragma unroll
    for (int it = 0; it < 4; ++it) {
      int rl = it * 8 + (lane >> 3), cc = lane & 7;
      *(int4*)(Mg + (long)(half * 32 + rl) * 1024 + cc * 16) =
          *(const int4*)(&eb[rl * 144 + cc * 16]);
    }
  }
}

// ---------------------------------------------------------------------------
// K4: per 64-row tile: LN(m) over c, m_ln @ Wpo, * g * mask -> dz fp32.
// Staging: 4 channels/thread packed into ds_write_b64 (4x fewer LDS ops,
// e-rotated against bank camping).  No obuf: g*mask fused into MFMA epilogue.
// ---------------------------------------------------------------------------
__global__ __launch_bounds__(256) void k_out(const unsigned short* __restrict__ m_t,
                                             const unsigned short* __restrict__ gbuf,
                                             const unsigned short* __restrict__ Wt,
                                             const int* __restrict__ maskp,
                                             const float* __restrict__ lnw,
                                             const float* __restrict__ lnb,
                                             float* __restrict__ out) {
  __shared__ unsigned char mln[64 * 272];   // [row][c] bf16, padded rows
  __shared__ float lw[128], lb[128], mk[64];
  const int t = threadIdx.x;
  const long r0 = (long)blockIdx.x * 64;

  {  // stage + transpose: thread owns 4 channels x 8 rows -> 8 ds_write_b64
    const int cgroup = t >> 3;     // 0..31, c = cgroup*4
    const int cc = t & 7;          // row-chunk of 8
    int4 rv[4];
#pragma unroll
    for (int ci = 0; ci < 4; ++ci)
      rv[ci] = *(const int4*)((const char*)m_t + (long)(cgroup * 4 + ci) * 524288 +
                              r0 * 2 + cc * 16);
#pragma unroll
    for (int e = 0; e < 8; ++e) {
      int er = (e + cc) & 7;       // rotate: rows mod 8 distinct across lanes
      uint2 pk;
      pk.x = (unsigned)((const unsigned short*)&rv[0])[er] |
             ((unsigned)((const unsigned short*)&rv[1])[er] << 16);
      pk.y = (unsigned)((const unsigned short*)&rv[2])[er] |
             ((unsigned)((const unsigned short*)&rv[3])[er] << 16);
      *(uint2*)(&mln[(cc * 8 + er) * 272 + cgroup * 8]) = pk;
    }
  }
  if (t < 128) { lw[t] = lnw[t]; lb[t] = lnb[t]; }
  if (t < 64) mk[t] = (float)maskp[r0 + t];
  __syncthreads();

  {  // LayerNorm over c: 4 threads per row; write m_ln back in place (bf16)
    int row = t >> 2, part = t & 3;
    float xv[32];
    float s = 0.f, q = 0.f;
#pragma unroll
    for (int jj = 0; jj < 16; ++jj) {
      unsigned u = *(const unsigned*)(&mln[row * 272 + part * 64 + jj * 4]);
      float x0 = bf2f((unsigned short)(u & 0xffff));
      float x1 = bf2f((unsigned short)(u >> 16));
      xv[2 * jj] = x0; xv[2 * jj + 1] = x1;
      s += x0 + x1; q += x0 * x0 + x1 * x1;
    }
    s += __shfl_xor(s, 1); q += __shfl_xor(q, 1);
    s += __shfl_xor(s, 2); q += __shfl_xor(q, 2);
    float mu = s * (1.f / 128.f);
    float var = q * (1.f / 128.f) - mu * mu;
    float rs = rsqrtf(var + EPSV);
#pragma unroll
    for (int jj = 0; jj < 16; ++jj) {
      int c = part * 32 + 2 * jj;
      unsigned short h0 = f2bf((xv[2 * jj] - mu) * rs * lw[c] + lb[c]);
      unsigned short h1 = f2bf((xv[2 * jj + 1] - mu) * rs * lw[c + 1] + lb[c + 1]);
      *(unsigned*)(&mln[row * 272 + c * 2]) = (unsigned)h0 | ((unsigned)h1 << 16);
    }
  }
  __syncthreads();

  // GEMM m_ln @ Wpo with fused g*mask epilogue, direct fp32 stores
  const int w = t >> 6, lane = t & 63;
  const int mn = lane & 15, q4 = lane >> 4;
  bf16x8 afr[4];
#pragma unroll
  for (int kk = 0; kk < 4; ++kk)
    afr[kk] = *(const bf16x8*)(&mln[(w * 16 + mn) * 272 + kk * 64 + q4 * 16]);
  const unsigned short* Wp = Wt + 5 * 16384;
#pragma unroll 1
  for (int nt = 0; nt < 8; ++nt) {
    f32x4 acc = {0.f, 0.f, 0.f, 0.f};
#pragma unroll
    for (int kk = 0; kk < 4; ++kk) {
      bf16x8 bfr = *(const bf16x8*)(Wp + (nt * 16 + mn) * 128 + kk * 32 + q4 * 8);
      acc = __builtin_amdgcn_mfma_f32_16x16x32_bf16(afr[kk], bfr, acc, 0, 0, 0);
    }
    const int cl = nt * 16 + mn;
#pragma unroll
    for (int r = 0; r < 4; ++r) {
      const int row = w * 16 + q4 * 4 + r;
      float gv = bf2f(gbuf[(r0 + row) * 128 + cl]);
      out[(r0 + row) * 128 + cl] = acc[r] * gv * mk[row];
    }
  }
}

// ---------------------------------------------------------------------------
extern "C" void kernel_launch(void* const* d_in, const int* in_sizes, int n_in,
                              void* d_out, int out_size, void* d_ws, size_t ws_size,
                              hipStream_t stream) {
  const float* z    = (const float*)d_in[0];
  const int* maskp  = (const int*)d_in[1];
  const float* lniw = (const float*)d_in[2];
  const float* lnib = (const float*)d_in[3];
  const float* lnow = (const float*)d_in[4];
  const float* lnob = (const float*)d_in[5];
  const float* Wpa  = (const float*)d_in[6];
  const float* Wga  = (const float*)d_in[7];
  const float* Wpb  = (const float*)d_in[8];
  const float* Wgb  = (const float*)d_in[9];
  const float* Wgo  = (const float*)d_in[10];
  const float* Wpo  = (const float*)d_in[11];
  float* out = (float*)d_out;

  char* ws = (char*)d_ws;
  unsigned short* a_f = (unsigned short*)(ws);                 // bf16 frag-major
  unsigned short* b_f = (unsigned short*)(ws + 67108864);      // bf16 frag-major
  unsigned short* g   = (unsigned short*)(ws + 134217728);     // bf16 [262144][128]
  unsigned short* m_t = (unsigned short*)(ws + 201326592);     // bf16 [128][262144]
  unsigned short* Wt  = (unsigned short*)(ws + 268435456);     // 6 x [128][128] bf16

  k_prep<<<384, 256, 0, stream>>>(Wpa, Wga, Wpb, Wgb, Wgo, Wpo, Wt);
  k_proj<<<4096, 256, 0, stream>>>(z, lniw, lnib, Wt, maskp, a_f, b_f, g);
  k_einsum<<<2048, 256, 0, stream>>>(a_f, b_f, m_t);
  k_out<<<4096, 256, 0, stream>>>(m_t, g, Wt, maskp, lnow, lnob, out);
}

// Round 6
// 572.313 us; speedup vs baseline: 1.1143x; 1.1143x over previous
//
#include <hip/hip_runtime.h>
#include <stdint.h>

#define LDIM 512
#define LLTOT 262144            // 512*512
#define EPSV 1e-5f

typedef short bf16x8 __attribute__((ext_vector_type(8)));
typedef float f32x4 __attribute__((ext_vector_type(4)));

__device__ __forceinline__ unsigned short f2bf(float f) {
  union { float f; unsigned u; } v; v.f = f;
  unsigned r = v.u + 0x7FFFu + ((v.u >> 16) & 1u);   // RNE
  return (unsigned short)(r >> 16);
}
__device__ __forceinline__ float bf2f(unsigned short h) {
  union { unsigned u; float f; } v; v.u = ((unsigned)h) << 16;
  return v.f;
}
__device__ __forceinline__ float sigm(float x) { return 1.0f / (1.0f + __expf(-x)); }

// Fragment-major layout for a/b intermediates (the einsum's operands):
//   element (ch, i, k) lives at
//   ch*524288 + (k>>5)*32768 + (i>>4)*1024 + ((i&15)*4 + ((k>>3)&3))*16 + (k&7)*2
// One (ch, k32, i16) chunk = 1 KB = exactly one wave's MFMA fragment load.

// ---------------------------------------------------------------------------
// K0: weights fp32 [c][o] -> bf16 transposed [o][c].  Order: ga,pa,gb,pb,go,po
// ---------------------------------------------------------------------------
__global__ void k_prep(const float* __restrict__ Wpa, const float* __restrict__ Wga,
                       const float* __restrict__ Wpb, const float* __restrict__ Wgb,
                       const float* __restrict__ Wgo, const float* __restrict__ Wpo,
                       unsigned short* __restrict__ Wt) {
  int t = blockIdx.x * blockDim.x + threadIdx.x;     // 0..98303
  int mat = t >> 14;
  int rem = t & 16383;
  int o = rem >> 7;
  int c = rem & 127;
  const float* src;
  switch (mat) {
    case 0: src = Wga; break;
    case 1: src = Wpa; break;
    case 2: src = Wgb; break;
    case 3: src = Wpb; break;
    case 4: src = Wgo; break;
    default: src = Wpo; break;
  }
  Wt[mat * 16384 + o * 128 + c] = f2bf(src[c * 128 + o]);
}

// ---------------------------------------------------------------------------
// K1 (fused LN + projections), weights-resident.  Per block: 128 flat positions
// (R4 config).  LN restructured: 16 interleaved rows per pass so the 6-level
// shfl chain's ~120cyc/level latency is amortized over 16 independent chains.
// ---------------------------------------------------------------------------
__global__ __launch_bounds__(256) void k_proj(const float* __restrict__ z,
                                              const float* __restrict__ lnw,
                                              const float* __restrict__ lnb,
                                              const unsigned short* __restrict__ Wt,
                                              const int* __restrict__ maskp,
                                              unsigned short* __restrict__ a_f,
                                              unsigned short* __restrict__ b_f,
                                              unsigned short* __restrict__ gout) {
  __shared__ unsigned char zbuf[128 * 272];   // rows padded 256->272B
  __shared__ float maskf[128];
  const int t = threadIdx.x;
  const int bid = blockIdx.x;
  const long r0 = (long)bid * 128;
  const int w = t >> 6, lane = t & 63;
  const int mn = lane & 15, q4 = lane >> 4;
  // fragment-layout constants for this block (i fixed, k0 = start col)
  const int k0 = (bid & 3) * 128;
  const int i16 = bid >> 6;            // (i>>4), i = bid>>2
  const int irem = (bid >> 2) & 15;    // i & 15

  if (t < 128) maskf[t] = (float)maskp[r0 + t];

  // fused input LayerNorm: wave handles 32 rows as 2 passes of 16 interleaved
  const float lw0 = lnw[2 * lane], lw1 = lnw[2 * lane + 1];
  const float lb0 = lnb[2 * lane], lb1 = lnb[2 * lane + 1];
#pragma unroll 1
  for (int pass = 0; pass < 2; ++pass) {
    const int rbase = w * 32 + pass * 16;
    float2 v[16];
#pragma unroll
    for (int i = 0; i < 16; ++i)
      v[i] = ((const float2*)(z + (r0 + rbase + i) * 128))[lane];
    float s[16], q[16];
#pragma unroll
    for (int i = 0; i < 16; ++i) {
      s[i] = v[i].x + v[i].y;
      q[i] = v[i].x * v[i].x + v[i].y * v[i].y;
    }
#pragma unroll
    for (int off = 32; off; off >>= 1) {
#pragma unroll
      for (int i = 0; i < 16; ++i) { s[i] += __shfl_xor(s[i], off); }
#pragma unroll
      for (int i = 0; i < 16; ++i) { q[i] += __shfl_xor(q[i], off); }
    }
#pragma unroll
    for (int i = 0; i < 16; ++i) {
      float mu = s[i] * (1.0f / 128.0f);
      float rs = rsqrtf(q[i] * (1.0f / 128.0f) - mu * mu + EPSV);
      ushort2 o;
      o.x = f2bf((v[i].x - mu) * rs * lw0 + lb0);
      o.y = f2bf((v[i].y - mu) * rs * lw1 + lb1);
      ((ushort2*)&zbuf[(rbase + i) * 272])[lane] = o;
    }
  }
  __syncthreads();

  // phases p=0 (a), p=1 (b): gate+proj weights resident in VGPRs
#pragma unroll 1
  for (int p = 0; p < 2; ++p) {
    const unsigned short* Wg = Wt + (p * 2) * 16384;
    const unsigned short* Wp = Wt + (p * 2 + 1) * 16384;
    unsigned short* dst = p ? b_f : a_f;
    bf16x8 wg[2][4], wp[2][4];
#pragma unroll
    for (int ntl = 0; ntl < 2; ++ntl)
#pragma unroll
      for (int kk = 0; kk < 4; ++kk) {
        const int o = (w * 2 + ntl) * 16 + mn;
        wg[ntl][kk] = *(const bf16x8*)(Wg + o * 128 + kk * 32 + q4 * 8);
        wp[ntl][kk] = *(const bf16x8*)(Wp + o * 128 + kk * 32 + q4 * 8);
      }
#pragma unroll 1
    for (int rg = 0; rg < 8; ++rg) {
      bf16x8 afr[4];
#pragma unroll
      for (int kk = 0; kk < 4; ++kk)
        afr[kk] = *(const bf16x8*)(&zbuf[(rg * 16 + mn) * 272 + kk * 64 + q4 * 16]);
      f32x4 aG[2] = {{0.f,0.f,0.f,0.f},{0.f,0.f,0.f,0.f}};
      f32x4 aP[2] = {{0.f,0.f,0.f,0.f},{0.f,0.f,0.f,0.f}};
#pragma unroll
      for (int kk = 0; kk < 4; ++kk)
#pragma unroll
        for (int ntl = 0; ntl < 2; ++ntl) {
          aG[ntl] = __builtin_amdgcn_mfma_f32_16x16x32_bf16(afr[kk], wg[ntl][kk], aG[ntl], 0, 0, 0);
          aP[ntl] = __builtin_amdgcn_mfma_f32_16x16x32_bf16(afr[kk], wp[ntl][kk], aP[ntl], 0, 0, 0);
        }
      const int rowb = rg * 16 + q4 * 4;        // k-offset within block (4 consec)
      const int kpos = k0 + rowb;               // global k of first element
      const int kc = kpos >> 5;
      const int cell = (irem * 4 + ((kpos >> 3) & 3)) * 16 + (kpos & 7) * 2;
#pragma unroll
      for (int ntl = 0; ntl < 2; ++ntl) {
        const int c = (w * 2 + ntl) * 16 + mn;
        unsigned short hv[4];
#pragma unroll
        for (int r = 0; r < 4; ++r)
          hv[r] = f2bf(sigm(aG[ntl][r]) * aP[ntl][r] * maskf[rowb + r]);
        uint2 pk;
        pk.x = (unsigned)hv[0] | ((unsigned)hv[1] << 16);
        pk.y = (unsigned)hv[2] | ((unsigned)hv[3] << 16);
        *(uint2*)((char*)dst + (long)c * 524288 + kc * 32768 + i16 * 1024 + cell) = pk;
      }
    }
  }

  {  // g phase: g = sigmoid(zln @ Wgo) -> gout[row][c] (direct 2B stores, L2 merges)
    const unsigned short* Wgp = Wt + 4 * 16384;
    bf16x8 wg[2][4];
#pragma unroll
    for (int ntl = 0; ntl < 2; ++ntl)
#pragma unroll
      for (int kk = 0; kk < 4; ++kk)
        wg[ntl][kk] = *(const bf16x8*)(Wgp + ((w * 2 + ntl) * 16 + mn) * 128 + kk * 32 + q4 * 8);
#pragma unroll 1
    for (int rg = 0; rg < 8; ++rg) {
      bf16x8 afr[4];
#pragma unroll
      for (int kk = 0; kk < 4; ++kk)
        afr[kk] = *(const bf16x8*)(&zbuf[(rg * 16 + mn) * 272 + kk * 64 + q4 * 16]);
      f32x4 aG[2] = {{0.f,0.f,0.f,0.f},{0.f,0.f,0.f,0.f}};
#pragma unroll
      for (int kk = 0; kk < 4; ++kk)
#pragma unroll
        for (int ntl = 0; ntl < 2; ++ntl)
          aG[ntl] = __builtin_amdgcn_mfma_f32_16x16x32_bf16(afr[kk], wg[ntl][kk], aG[ntl], 0, 0, 0);
      const int rowb = rg * 16 + q4 * 4;
#pragma unroll
      for (int ntl = 0; ntl < 2; ++ntl) {
        const int c = (w * 2 + ntl) * 16 + mn;
#pragma unroll
        for (int r = 0; r < 4; ++r)
          gout[(r0 + rowb + r) * 128 + c] = f2bf(sigm(aG[ntl][r]));
      }
    }
  }
}

// ---------------------------------------------------------------------------
// K3: per-channel GEMM  m_c = a_c @ b_c^T from FRAGMENT-MAJOR operands.
// No LDS staging, no barriers.  Prefetch depth 2 (3 rotating buffers) so
// ~160cyc of L2 latency is covered per chunk instead of ~80.
// ---------------------------------------------------------------------------
__global__ __launch_bounds__(256) void k_einsum(const unsigned short* __restrict__ af_g,
                                                const unsigned short* __restrict__ bf_g,
                                                unsigned short* __restrict__ m_t) {
  __shared__ unsigned char shm[36864];   // epilogue bounce only (per-wave 9216B)
  const int t = threadIdx.x;
  const int w = t >> 6, lane = t & 63;
  const int bid = blockIdx.x;
  const int xcd = bid & 7;               // round-robin bid%8 -> XCD
  const int j = bid >> 3;
  const int ch = xcd * 16 + (j >> 4);    // 16 channels per XCD
  const int tile = j & 15;
  const int ti = tile >> 2, tj = tile & 3;
  const int wr = w >> 1, wc = w & 1;
  const int mn = lane & 15, q4 = lane >> 4;
  const int loff = (mn * 4 + q4) * 16;   // cell order: (i&15)*4 + k-subchunk
  const char* Af = (const char*)af_g + (long)ch * 524288 + (ti * 8 + wr * 4) * 1024 + loff;
  const char* Bf = (const char*)bf_g + (long)ch * 524288 + (tj * 8 + wc * 4) * 1024 + loff;

  f32x4 acc[4][4];
#pragma unroll
  for (int i = 0; i < 4; ++i)
#pragma unroll
    for (int jj = 0; jj < 4; ++jj) acc[i][jj] = (f32x4){0.f, 0.f, 0.f, 0.f};

  bf16x8 afr[3][4], bfr[3][4];
#define LOADFRAG(buf, k32)                                                    \
  {                                                                           \
    _Pragma("unroll")                                                         \
    for (int mt = 0; mt < 4; ++mt)                                            \
      afr[buf][mt] = *(const bf16x8*)(Af + (k32) * 32768 + mt * 1024);        \
    _Pragma("unroll")                                                         \
    for (int nt = 0; nt < 4; ++nt)                                            \
      bfr[buf][nt] = *(const bf16x8*)(Bf + (k32) * 32768 + nt * 1024);        \
  }
#define MFMABLK(buf)                                                          \
  {                                                                           \
    _Pragma("unroll")                                                         \
    for (int mt = 0; mt < 4; ++mt)                                            \
      _Pragma("unroll")                                                       \
      for (int nt = 0; nt < 4; ++nt)                                          \
        acc[mt][nt] = __builtin_amdgcn_mfma_f32_16x16x32_bf16(                \
            afr[buf][mt], bfr[buf][nt], acc[mt][nt], 0, 0, 0);                \
  }

  LOADFRAG(0, 0)
  LOADFRAG(1, 1)
#pragma unroll
  for (int k32 = 0; k32 < 16; ++k32) {
    if (k32 + 2 < 16) LOADFRAG((k32 + 2) % 3, k32 + 2)
    MFMABLK(k32 % 3)
  }
#undef LOADFRAG
#undef MFMABLK

  // epilogue: per-wave LDS bounce (rows padded to 144B), coalesced bf16 store.
  // eb is wave-private -> no __syncthreads needed.
  unsigned char* eb = shm + w * 9216;
#pragma unroll
  for (int mt = 0; mt < 4; ++mt)
#pragma unroll
    for (int nt = 0; nt < 4; ++nt)
#pragma unroll
      for (int r = 0; r < 4; ++r) {
        int rl = mt * 16 + q4 * 4 + r;
        int cl = nt * 16 + mn;
        *(unsigned short*)(&eb[rl * 144 + cl * 2]) = f2bf(acc[mt][nt][r]);
      }
  char* Mg = (char*)m_t + (long)ch * 524288 +
             (long)(ti * 128 + wr * 64) * 1024 + (tj * 128 + wc * 64) * 2;
#pragma unroll
  for (int it = 0; it < 8; ++it) {
    int rl = it * 8 + (lane >> 3), cc = lane & 7;
    *(int4*)(Mg + (long)rl * 1024 + cc * 16) = *(const int4*)(&eb[rl * 144 + cc * 16]);
  }
}

// ---------------------------------------------------------------------------
// K4: per 64-row tile: LN(m) over c, m_ln @ Wpo, * g * mask -> dz fp32.
// R4 structure (obuf + coalesced epilogue); staging packed into ds_write_b64
// (4 channels/thread, e-rotated against bank camping).
// ---------------------------------------------------------------------------
__global__ __launch_bounds__(256) void k_out(const unsigned short* __restrict__ m_t,
                                             const unsigned short* __restrict__ gbuf,
                                             const unsigned short* __restrict__ Wt,
                                             const int* __restrict__ maskp,
                                             const float* __restrict__ lnw,
                                             const float* __restrict__ lnb,
                                             float* __restrict__ out) {
  __shared__ unsigned char mln[64 * 272];   // [row][c] bf16, padded rows
  __shared__ float obuf[64 * 132];          // [row][c] fp32, padded rows
  __shared__ float lw[128], lb[128], mk[64];
  const int t = threadIdx.x;
  const long r0 = (long)blockIdx.x * 64;

  {  // stage + transpose: thread owns 4 channels x 8 rows -> 8 ds_write_b64
    const int cgroup = t >> 3;     // 0..31, c = cgroup*4
    const int cc = t & 7;          // row-chunk of 8
    int4 rv[4];
#pragma unroll
    for (int ci = 0; ci < 4; ++ci)
      rv[ci] = *(const int4*)((const char*)m_t + (long)(cgroup * 4 + ci) * 524288 +
                              r0 * 2 + cc * 16);
#pragma unroll
    for (int e = 0; e < 8; ++e) {
      int er = (e + cc) & 7;       // rotate: rows mod 8 distinct across lanes
      uint2 pk;
      pk.x = (unsigned)((const unsigned short*)&rv[0])[er] |
             ((unsigned)((const unsigned short*)&rv[1])[er] << 16);
      pk.y = (unsigned)((const unsigned short*)&rv[2])[er] |
             ((unsigned)((const unsigned short*)&rv[3])[er] << 16);
      *(uint2*)(&mln[(cc * 8 + er) * 272 + cgroup * 8]) = pk;
    }
  }
  if (t < 128) { lw[t] = lnw[t]; lb[t] = lnb[t]; }
  if (t < 64) mk[t] = (float)maskp[r0 + t];
  __syncthreads();

  {  // LayerNorm over c: 4 threads per row; write m_ln back in place (bf16)
    int row = t >> 2, part = t & 3;
    float xv[32];
    float s = 0.f, q = 0.f;
#pragma unroll
    for (int jj = 0; jj < 16; ++jj) {
      unsigned u = *(const unsigned*)(&mln[row * 272 + part * 64 + jj * 4]);
      float x0 = bf2f((unsigned short)(u & 0xffff));
      float x1 = bf2f((unsigned short)(u >> 16));
      xv[2 * jj] = x0; xv[2 * jj + 1] = x1;
      s += x0 + x1; q += x0 * x0 + x1 * x1;
    }
    s += __shfl_xor(s, 1); q += __shfl_xor(q, 1);
    s += __shfl_xor(s, 2); q += __shfl_xor(q, 2);
    float mu = s * (1.f / 128.f);
    float var = q * (1.f / 128.f) - mu * mu;
    float rs = rsqrtf(var + EPSV);
#pragma unroll
    for (int jj = 0; jj < 16; ++jj) {
      int c = part * 32 + 2 * jj;
      unsigned short h0 = f2bf((xv[2 * jj] - mu) * rs * lw[c] + lb[c]);
      unsigned short h1 = f2bf((xv[2 * jj + 1] - mu) * rs * lw[c + 1] + lb[c + 1]);
      *(unsigned*)(&mln[row * 272 + c * 2]) = (unsigned)h0 | ((unsigned)h1 << 16);
    }
  }
  __syncthreads();

  // GEMM: m_ln @ Wpo -> obuf (raw acc)
  const int w = t >> 6, lane = t & 63;
  const int mn = lane & 15, q4 = lane >> 4;
  bf16x8 afr[4];
#pragma unroll
  for (int kk = 0; kk < 4; ++kk)
    afr[kk] = *(const bf16x8*)(&mln[(w * 16 + mn) * 272 + kk * 64 + q4 * 16]);
  const unsigned short* Wp = Wt + 5 * 16384;
#pragma unroll 1
  for (int nt = 0; nt < 8; ++nt) {
    f32x4 acc = {0.f, 0.f, 0.f, 0.f};
#pragma unroll
    for (int kk = 0; kk < 4; ++kk) {
      bf16x8 bfr = *(const bf16x8*)(Wp + (nt * 16 + mn) * 128 + kk * 32 + q4 * 8);
      acc = __builtin_amdgcn_mfma_f32_16x16x32_bf16(afr[kk], bfr, acc, 0, 0, 0);
    }
    const int cl = nt * 16 + mn;
#pragma unroll
    for (int r = 0; r < 4; ++r)
      obuf[(w * 16 + q4 * 4 + r) * 132 + cl] = acc[r];
  }
  __syncthreads();

  // out = obuf * g * mask (coalesced; g read as bf16x4 chunks)
#pragma unroll
  for (int it = 0; it < 8; ++it) {
    int chunk = it * 256 + t;
    int row = chunk >> 5, cc = chunk & 31;
    float4 v = *(const float4*)(&obuf[row * 132 + cc * 4]);
    uint2 gp = *(const uint2*)((const char*)gbuf + (r0 + row) * 256 + cc * 8);
    float mval = mk[row];
    v.x *= bf2f((unsigned short)(gp.x & 0xffff)) * mval;
    v.y *= bf2f((unsigned short)(gp.x >> 16)) * mval;
    v.z *= bf2f((unsigned short)(gp.y & 0xffff)) * mval;
    v.w *= bf2f((unsigned short)(gp.y >> 16)) * mval;
    *(float4*)(out + (r0 + row) * 128 + cc * 4) = v;
  }
}

// ---------------------------------------------------------------------------
extern "C" void kernel_launch(void* const* d_in, const int* in_sizes, int n_in,
                              void* d_out, int out_size, void* d_ws, size_t ws_size,
                              hipStream_t stream) {
  const float* z    = (const float*)d_in[0];
  const int* maskp  = (const int*)d_in[1];
  const float* lniw = (const float*)d_in[2];
  const float* lnib = (const float*)d_in[3];
  const float* lnow = (const float*)d_in[4];
  const float* lnob = (const float*)d_in[5];
  const float* Wpa  = (const float*)d_in[6];
  const float* Wga  = (const float*)d_in[7];
  const float* Wpb  = (const float*)d_in[8];
  const float* Wgb  = (const float*)d_in[9];
  const float* Wgo  = (const float*)d_in[10];
  const float* Wpo  = (const float*)d_in[11];
  float* out = (float*)d_out;

  char* ws = (char*)d_ws;
  unsigned short* a_f = (unsigned short*)(ws);                 // bf16 frag-major
  unsigned short* b_f = (unsigned short*)(ws + 67108864);      // bf16 frag-major
  unsigned short* g   = (unsigned short*)(ws + 134217728);     // bf16 [262144][128]
  unsigned short* m_t = (unsigned short*)(ws + 201326592);     // bf16 [128][262144]
  unsigned short* Wt  = (unsigned short*)(ws + 268435456);     // 6 x [128][128] bf16

  k_prep<<<384, 256, 0, stream>>>(Wpa, Wga, Wpb, Wgb, Wgo, Wpo, Wt);
  k_proj<<<2048, 256, 0, stream>>>(z, lniw, lnib, Wt, maskp, a_f, b_f, g);
  k_einsum<<<2048, 256, 0, stream>>>(a_f, b_f, m_t);
  k_out<<<4096, 256, 0, stream>>>(m_t, g, Wt, maskp, lnow, lnob, out);
}